// Round 7
// baseline (246.881 us; speedup 1.0000x reference)
//
#include <hip/hip_runtime.h>

typedef __attribute__((ext_vector_type(8))) _Float16 half8;
typedef __attribute__((ext_vector_type(4))) _Float16 half4v;
typedef __attribute__((ext_vector_type(4))) float floatx4;

#define NB 128
#define NN 64
#define NV 14
#define PP 32
#define SS 14
#define HH 128
#define DE 64
#define NCLS 5
#define PITCH 136   // halves; 272 B rows -> max 2-way bank aliasing (free)

// fragment-major weight offsets (halves). layout: [nt][ks][lane][8]
#define OFF_W2   0
#define OFF_W3   16384
#define OFF_W2PV 24576
#define OFF_W3PV 40960
#define OFF_FO1  49152
#define OFF_FO2  69632
#define OFF_FO3  86016

__device__ __forceinline__ floatx4 MFMA(half8 a, half8 b, floatx4 c) {
  return __builtin_amdgcn_mfma_f32_16x16x32_f16(a, b, c, 0, 0, 0);
}

// relu(acc+bias) -> 4 fp16 packed in 2 u32 (rg0|rg1, rg2|rg3)
__device__ __forceinline__ uint2 pack4(floatx4 a, float4 bb) {
  half4v h;
  h[0] = (_Float16)fmaxf(a[0] + bb.x, 0.f);
  h[1] = (_Float16)fmaxf(a[1] + bb.y, 0.f);
  h[2] = (_Float16)fmaxf(a[2] + bb.z, 0.f);
  h[3] = (_Float16)fmaxf(a[3] + bb.w, 0.f);
  union { half4v h4; uint2 u; } cv; cv.h4 = h;
  return cv.u;
}

// ---------------- K0: fp16 layer-1 terms (+bias fold), frag-major weights, d_out zero ----------------
__global__ __launch_bounds__(256) void k0_prep(
    const float* __restrict__ x, const float* __restrict__ y,
    const float* __restrict__ fr1_w, const float* __restrict__ fr1_b,
    const float* __restrict__ fr1pv_w, const float* __restrict__ fr1pv_b,
    const float* __restrict__ fr2_w, const float* __restrict__ fr3_w,
    const float* __restrict__ fr2pv_w, const float* __restrict__ fr3pv_w,
    const float* __restrict__ fo1_w, const float* __restrict__ fo2_w,
    const float* __restrict__ fo3_w,
    _Float16* __restrict__ A1h, _Float16* __restrict__ B1h,
    _Float16* __restrict__ A1pvh, _Float16* __restrict__ B1pvh,
    _Float16* __restrict__ WT, float* __restrict__ dout) {
  int blk = blockIdx.x;
  int tid = threadIdx.x;
  if (blk < 768) {
    // half of one (matrix, batch): 32 rows x 128 cols, K=32
    int mat = blk >> 8, sub = blk & 255;
    int b = sub >> 1, n0 = (sub & 1) << 5;
    __shared__ float sxT[32 * 33];
    for (int i = tid; i < 32 * PP; i += 256) {
      int p = i >> 5, n = i & 31;
      sxT[n * 33 + p] = x[b * (PP * NN) + p * 64 + n0 + n];
    }
    __syncthreads();
    const float* w; _Float16* outp; const float* bias;
    if (mat == 0)      { w = fr1_w;           outp = A1h;   bias = fr1_b; }
    else if (mat == 1) { w = fr1_w + 32 * HH; outp = B1h;   bias = nullptr; }
    else               { w = fr1pv_w;         outp = A1pvh; bias = fr1pv_b; }
    for (int o = tid; o < 32 * 32; o += 256) {
      int n = o >> 5, jc = o & 31;
      float4 acc = {0.f, 0.f, 0.f, 0.f};
      const float* xr = &sxT[n * 33];
#pragma unroll 8
      for (int k = 0; k < PP; k++) {
        float xv = xr[k];
        float4 wv = ((const float4*)w)[k * 32 + jc];
        acc.x += xv * wv.x; acc.y += xv * wv.y;
        acc.z += xv * wv.z; acc.w += xv * wv.w;
      }
      if (bias) {
        float4 bv = ((const float4*)bias)[jc];
        acc.x += bv.x; acc.y += bv.y; acc.z += bv.z; acc.w += bv.w;
      }
      half4v hv;
      hv[0] = (_Float16)acc.x; hv[1] = (_Float16)acc.y;
      hv[2] = (_Float16)acc.z; hv[3] = (_Float16)acc.w;
      *(half4v*)(&outp[(b * NN + n0 + n) * HH + jc * 4]) = hv;
    }
  } else if (blk < 896) {
    int b = blk - 768;
    __shared__ float syT[NV * 15];
    for (int i = tid; i < SS * NV; i += 256) {
      int s = i / NV, v = i - s * NV;
      syT[v * 15 + s] = y[b * (SS * NV) + i];
    }
    __syncthreads();
    const float4* w4 = (const float4*)(fr1pv_w + 32 * HH);
    for (int o = tid; o < NV * 32; o += 256) {
      int v = o >> 5, jc = o & 31;
      float4 acc = {0.f, 0.f, 0.f, 0.f};
#pragma unroll
      for (int s = 0; s < SS; s++) {
        float yv = syT[v * 15 + s];
        float4 wv = w4[s * 32 + jc];
        acc.x += yv * wv.x; acc.y += yv * wv.y;
        acc.z += yv * wv.z; acc.w += yv * wv.w;
      }
      half4v hv;
      hv[0] = (_Float16)acc.x; hv[1] = (_Float16)acc.y;
      hv[2] = (_Float16)acc.z; hv[3] = (_Float16)acc.w;
      *(half4v*)(&B1pvh[(b * NV + v) * HH + jc * 4]) = hv;
    }
  } else if (blk < 903) {
    // frag-major: dst[((nt*NKS+ks)*64 + lane)*8 + j] = src[(ks*32+q*8+j)*N + nt*16+c]
    int wid = blk - 896;
    const float* src; int N, NKS, NTN; _Float16* dst;
    switch (wid) {
      case 0: src = fr2_w;   N = 128; NKS = 4; NTN = 8; dst = WT + OFF_W2;   break;
      case 1: src = fr3_w;   N = 64;  NKS = 4; NTN = 4; dst = WT + OFF_W3;   break;
      case 2: src = fr2pv_w; N = 128; NKS = 4; NTN = 8; dst = WT + OFF_W2PV; break;
      case 3: src = fr3pv_w; N = 64;  NKS = 4; NTN = 4; dst = WT + OFF_W3PV; break;
      case 4: src = fo1_w;   N = 128; NKS = 5; NTN = 8; dst = WT + OFF_FO1;  break;
      case 5: src = fo2_w;   N = 128; NKS = 4; NTN = 8; dst = WT + OFF_FO2;  break;
      default: src = fo3_w;  N = 64;  NKS = 4; NTN = 4; dst = WT + OFF_FO3;  break;
    }
    int tot = NTN * NKS * 512;
    for (int i = tid; i < tot; i += 256) {
      int j = i & 7, l = (i >> 3) & 63, f = i >> 9;
      int ks = f % NKS, nt = f / NKS;
      int cc = l & 15, qq = l >> 4;
      dst[i] = (_Float16)src[(ks * 32 + qq * 8 + j) * N + nt * 16 + cc];
    }
  } else {
    for (int i = tid; i < NB * NCLS; i += 256) dout[i] = 0.f;
  }
}

// layers 2+3 on one 16-row wave tile; transposed-C layer2 output converted to
// layer3 A-frags IN REGISTER via quad-shuffles (no LDS round-trip, no barrier).
template <int DIVR, int NROWS>
__device__ __forceinline__ void layers23(
    const half8 (&hf)[4],
    const _Float16* __restrict__ W2fm, const _Float16* __restrict__ W3fm,
    const float* __restrict__ b2, const float* __restrict__ b3,
    float* __restrict__ sEb, int rbase0, int lane) {
  int c = lane & 15, q = lane >> 4;
  int srcA = c + (((2 * q) & 3) << 4);
  int srcB = c + (((2 * q + 1) & 3) << 4);
  bool selhi = (q >> 1) != 0;
  half8 a2[4];
#pragma unroll
  for (int p = 0; p < 4; p++) {
    uint2 u0, u1;
    {  // nt even
      int nt = 2 * p;
      floatx4 acc = {0.f, 0.f, 0.f, 0.f};
#pragma unroll
      for (int ks = 0; ks < 4; ks++) {
        half8 wf = *(const half8*)(&W2fm[((nt * 4 + ks) << 9) + (lane << 3)]);
        acc = MFMA(wf, hf[ks], acc);
      }
      float4 bb = *(const float4*)(&b2[nt * 16 + q * 4]);
      u0 = pack4(acc, bb);
    }
    {  // nt odd
      int nt = 2 * p + 1;
      floatx4 acc = {0.f, 0.f, 0.f, 0.f};
#pragma unroll
      for (int ks = 0; ks < 4; ks++) {
        half8 wf = *(const half8*)(&W2fm[((nt * 4 + ks) << 9) + (lane << 3)]);
        acc = MFMA(wf, hf[ks], acc);
      }
      float4 bb = *(const float4*)(&b2[nt * 16 + q * 4]);
      u1 = pack4(acc, bb);
    }
    int ax0 = __shfl((int)u0.x, srcA), ax1 = __shfl((int)u1.x, srcA);
    int ay0 = __shfl((int)u0.y, srcA), ay1 = __shfl((int)u1.y, srcA);
    int bx0 = __shfl((int)u0.x, srcB), bx1 = __shfl((int)u1.x, srcB);
    int by0 = __shfl((int)u0.y, srcB), by1 = __shfl((int)u1.y, srcB);
    union { uint4 u; half8 h; } fr;
    fr.u.x = (unsigned)(selhi ? ax1 : ax0);
    fr.u.y = (unsigned)(selhi ? ay1 : ay0);
    fr.u.z = (unsigned)(selhi ? bx1 : bx0);
    fr.u.w = (unsigned)(selhi ? by1 : by0);
    a2[p] = fr.h;
  }
  // layer3: E = h2(A regs) @ W3(B from L1-hot global)
#pragma unroll
  for (int nt = 0; nt < 4; nt++) {
    floatx4 e = {0.f, 0.f, 0.f, 0.f};
#pragma unroll
    for (int ks = 0; ks < 4; ks++) {
      half8 wf = *(const half8*)(&W3fm[((nt * 4 + ks) << 9) + (lane << 3)]);
      e = MFMA(a2[ks], wf, e);
    }
    int col = nt * 16 + c;
    float bb = b3[col];
    int rbase = rbase0 + q * 4;
    if (rbase < NROWS) {
      float v0 = fmaxf(e[0] + bb, 0.f);
      float v1 = fmaxf(e[1] + bb, 0.f);
      float v2 = fmaxf(e[2] + bb, 0.f);
      float v3 = fmaxf(e[3] + bb, 0.f);
      int rrA = rbase / DIVR, rrB = (rbase + 3) / DIVR;
      if (rrA == rrB && rbase + 3 < NROWS) {
        atomicAdd(&sEb[rrA * 64 + col], v0 + v1 + v2 + v3);
      } else {
        float vs[4] = {v0, v1, v2, v3};
#pragma unroll
        for (int rg = 0; rg < 4; rg++) {
          int r2 = rbase + rg;
          if (r2 < NROWS) atomicAdd(&sEb[(r2 / DIVR) * 64 + col], vs[rg]);
        }
      }
    }
  }
}

// ---------------- MEGA: pp + pv edges + node MLP + pool + fc, per (b, 8 nodes) ----------------
__global__ __launch_bounds__(256) void mega(
    const _Float16* __restrict__ A1h, const _Float16* __restrict__ B1h,
    const _Float16* __restrict__ A1pvh, const _Float16* __restrict__ B1pvh,
    const float* __restrict__ x,
    const float* __restrict__ fr2_b, const float* __restrict__ fr3_b,
    const float* __restrict__ fr2pv_b, const float* __restrict__ fr3pv_b,
    const float* __restrict__ fo1_b, const float* __restrict__ fo2_b,
    const float* __restrict__ fo3_b,
    const float* __restrict__ fc_w, const float* __restrict__ fc_b,
    const _Float16* __restrict__ WT, float* __restrict__ out) {
  __shared__ _Float16 sB1[64 * PITCH];    // 17408 B; node-stage arrays overlay after edges
  __shared__ _Float16 sA1[8 * PITCH];     // 2176 B
  __shared__ _Float16 sApv[8 * PITCH];    // 2176 B
  __shared__ _Float16 sBpv[14 * PITCH];   // 3808 B
  __shared__ float sEpp[8 * 64];          // 2048 B
  __shared__ float sEpv[8 * 64];          // 2048 B
  __shared__ float sPool[64];             // 256 B     total ~29.9 KB
  int tid = threadIdx.x;
  int b = blockIdx.x >> 3, r0 = (blockIdx.x & 7) << 3;
  for (int i = tid; i < 512; i += 256) { sEpp[i] = 0.f; sEpv[i] = 0.f; }
  for (int i = tid; i < 64 * 16; i += 256) {
    int row = i >> 4, cc = i & 15;
    *(uint4*)(&sB1[row * PITCH + cc * 8]) = *(const uint4*)(&B1h[(b * NN + row) * HH + cc * 8]);
  }
  for (int i = tid; i < 8 * 16; i += 256) {
    int row = i >> 4, cc = i & 15;
    *(uint4*)(&sA1[row * PITCH + cc * 8]) = *(const uint4*)(&A1h[(b * NN + r0 + row) * HH + cc * 8]);
    *(uint4*)(&sApv[row * PITCH + cc * 8]) = *(const uint4*)(&A1pvh[(b * NN + r0 + row) * HH + cc * 8]);
  }
  for (int i = tid; i < 14 * 16; i += 256) {
    int row = i >> 4, cc = i & 15;
    *(uint4*)(&sBpv[row * PITCH + cc * 8]) = *(const uint4*)(&B1pvh[(b * NV + row) * HH + cc * 8]);
  }
  __syncthreads();
  int lane = tid & 63, wv = tid >> 6;
  int c = lane & 15, q = lane >> 4;
  // ---- 8 pp chunks of 64 rows (504 real rows: 8 receivers x 63 senders) ----
#pragma unroll 1
  for (int ch = 0; ch < 8; ch++) {
    int rbase0 = ch * 64 + wv * 16;
    int rl = rbase0 + c;
    int rr = rl / 63; if (rr > 7) rr = 7;
    int jj = rl - rr * 63; if (jj > 62) jj = 62;
    int s = jj + (jj >= r0 + rr ? 1 : 0);
    half8 hf[4];
#pragma unroll
    for (int ks = 0; ks < 4; ks++) {
      half8 av = *(const half8*)(&sA1[rr * PITCH + ks * 32 + q * 8]);
      half8 bv = *(const half8*)(&sB1[s * PITCH + ks * 32 + q * 8]);
      half8 h = av + bv;
#pragma unroll
      for (int j = 0; j < 8; j++) h[j] = h[j] > (_Float16)0.f ? h[j] : (_Float16)0.f;
      hf[ks] = h;
    }
    layers23<63, 504>(hf, WT + OFF_W2, WT + OFF_W3, fr2_b, fr3_b,
                      sEpp, rbase0, lane);
  }
  // ---- 2 pv chunks of 64 rows (112 real rows: 8 k-nodes x 14 vertices) ----
#pragma unroll 1
  for (int ch = 0; ch < 2; ch++) {
    int rbase0 = ch * 64 + wv * 16;
    int rl = rbase0 + c;
    int rr = rl / 14; if (rr > 7) rr = 7;
    int v = rl - rr * 14; if (v > 13) v = 13;
    half8 hf[4];
#pragma unroll
    for (int ks = 0; ks < 4; ks++) {
      half8 av = *(const half8*)(&sApv[rr * PITCH + ks * 32 + q * 8]);
      half8 bv = *(const half8*)(&sBpv[v * PITCH + ks * 32 + q * 8]);
      half8 h = av + bv;
#pragma unroll
      for (int j = 0; j < 8; j++) h[j] = h[j] > (_Float16)0.f ? h[j] : (_Float16)0.f;
      hf[ks] = h;
    }
    layers23<14, 112>(hf, WT + OFF_W2PV, WT + OFF_W3PV, fr2pv_b, fr3pv_b,
                      sEpv, rbase0, lane);
  }
  __syncthreads();   // sEb complete; sB1 dead -> overlay node arrays
  // ---- node stage: C = [x | Ebar_pp | Ebar_pv] for this block's 8 nodes ----
  _Float16* sC  = sB1;                 // 16 x 168 = 5376 B
  _Float16* sHa = sB1 + 16 * 168;      // 16 x PITCH = 4352 B
  _Float16* sHb = sB1 + 16 * 168 + 16 * PITCH;  // 4352 B (total 14080 <= 17408)
  for (int i = tid; i < 16 * 32; i += 256) {
    int row = i >> 5, p = i & 31;
    float v = (row < 8) ? x[b * (PP * NN) + p * 64 + r0 + row] : 0.f;
    sC[row * 168 + p] = (_Float16)v;
  }
  for (int i = tid; i < 16 * 64; i += 256) {
    int row = i >> 6, d = i & 63;
    float vpp = (row < 8) ? sEpp[row * 64 + d] : 0.f;
    float vpv = (row < 8) ? sEpv[row * 64 + d] : 0.f;
    sC[row * 168 + 32 + d] = (_Float16)vpp;
    sC[row * 168 + 96 + d] = (_Float16)vpv;
  }
  __syncthreads();
  // fo1 (K=160), transposed-C; wave owns cols wv*32..+31
  half8 cf[5];
#pragma unroll
  for (int ks = 0; ks < 5; ks++)
    cf[ks] = *(const half8*)(&sC[c * 168 + ks * 32 + q * 8]);
#pragma unroll
  for (int nt2 = 0; nt2 < 2; nt2++) {
    int nt = wv * 2 + nt2;
    floatx4 a0 = {0.f, 0.f, 0.f, 0.f};
#pragma unroll
    for (int ks = 0; ks < 5; ks++) {
      half8 wf = *(const half8*)(&WT[OFF_FO1 + ((nt * 5 + ks) << 9) + (lane << 3)]);
      a0 = MFMA(wf, cf[ks], a0);
    }
    float4 bb = *(const float4*)(&fo1_b[nt * 16 + q * 4]);
    half4v h0;
    h0[0] = (_Float16)fmaxf(a0[0] + bb.x, 0.f);
    h0[1] = (_Float16)fmaxf(a0[1] + bb.y, 0.f);
    h0[2] = (_Float16)fmaxf(a0[2] + bb.z, 0.f);
    h0[3] = (_Float16)fmaxf(a0[3] + bb.w, 0.f);
    *(half4v*)(&sHa[c * PITCH + nt * 16 + q * 4]) = h0;
  }
  __syncthreads();
  // fo2 (K=128), transposed-C
  half8 g1[4];
#pragma unroll
  for (int ks = 0; ks < 4; ks++)
    g1[ks] = *(const half8*)(&sHa[c * PITCH + ks * 32 + q * 8]);
#pragma unroll
  for (int nt2 = 0; nt2 < 2; nt2++) {
    int nt = wv * 2 + nt2;
    floatx4 a0 = {0.f, 0.f, 0.f, 0.f};
#pragma unroll
    for (int ks = 0; ks < 4; ks++) {
      half8 wf = *(const half8*)(&WT[OFF_FO2 + ((nt * 4 + ks) << 9) + (lane << 3)]);
      a0 = MFMA(wf, g1[ks], a0);
    }
    float4 bb = *(const float4*)(&fo2_b[nt * 16 + q * 4]);
    half4v h0;
    h0[0] = (_Float16)fmaxf(a0[0] + bb.x, 0.f);
    h0[1] = (_Float16)fmaxf(a0[1] + bb.y, 0.f);
    h0[2] = (_Float16)fmaxf(a0[2] + bb.z, 0.f);
    h0[3] = (_Float16)fmaxf(a0[3] + bb.w, 0.f);
    *(half4v*)(&sHb[c * PITCH + nt * 16 + q * 4]) = h0;
  }
  __syncthreads();
  // fo3 (N=64): wave owns 16 cols; pool over the 8 real nodes
  half8 g2[4];
#pragma unroll
  for (int ks = 0; ks < 4; ks++)
    g2[ks] = *(const half8*)(&sHb[c * PITCH + ks * 32 + q * 8]);
  floatx4 e0 = {0.f, 0.f, 0.f, 0.f};
#pragma unroll
  for (int ks = 0; ks < 4; ks++) {
    half8 wf = *(const half8*)(&WT[OFF_FO3 + ((wv * 4 + ks) << 9) + (lane << 3)]);
    e0 = MFMA(g2[ks], wf, e0);
  }
  float bb3 = fo3_b[wv * 16 + c];
  float s = 0.f;
  if (q < 2) {
#pragma unroll
    for (int rg = 0; rg < 4; rg++) s += fmaxf(e0[rg] + bb3, 0.f);
  }
  s += __shfl_xor(s, 16);
  if (lane < 16) sPool[wv * 16 + c] = s;
  __syncthreads();
  if (tid < NCLS) {
    float o = (r0 == 0) ? fc_b[tid] : 0.f;
#pragma unroll
    for (int d = 0; d < 64; d++) o += sPool[d] * fc_w[d * NCLS + tid];
    atomicAdd(&out[b * NCLS + tid], o);
  }
}

extern "C" void kernel_launch(void* const* d_in, const int* in_sizes, int n_in,
                              void* d_out, int out_size, void* d_ws, size_t ws_size,
                              hipStream_t stream) {
  const float* x = (const float*)d_in[0];
  const float* y = (const float*)d_in[1];
  const float* fr1_w = (const float*)d_in[2];  const float* fr1_b = (const float*)d_in[3];
  const float* fr2_w = (const float*)d_in[4];  const float* fr2_b = (const float*)d_in[5];
  const float* fr3_w = (const float*)d_in[6];  const float* fr3_b = (const float*)d_in[7];
  const float* fr1pv_w = (const float*)d_in[8];  const float* fr1pv_b = (const float*)d_in[9];
  const float* fr2pv_w = (const float*)d_in[10]; const float* fr2pv_b = (const float*)d_in[11];
  const float* fr3pv_w = (const float*)d_in[12]; const float* fr3pv_b = (const float*)d_in[13];
  const float* fo1_w = (const float*)d_in[14];  const float* fo1_b = (const float*)d_in[15];
  const float* fo2_w = (const float*)d_in[16];  const float* fo2_b = (const float*)d_in[17];
  const float* fo3_w = (const float*)d_in[18];  const float* fo3_b = (const float*)d_in[19];
  const float* fc_w = (const float*)d_in[20];   const float* fc_b = (const float*)d_in[21];

  char* ws = (char*)d_ws;
  _Float16* A1h   = (_Float16*)(ws);                 // [128][64][128] fp16 (bias folded)
  _Float16* B1h   = (_Float16*)(ws + (2u << 20));
  _Float16* A1pvh = (_Float16*)(ws + (4u << 20));    // (bias folded)
  _Float16* B1pvh = (_Float16*)(ws + (6u << 20));    // [128][14][128] fp16
  _Float16* WT    = (_Float16*)(ws + (7u << 20));    // frag-major fp16 weights (~200 KB)

  k0_prep<<<904, 256, 0, stream>>>(x, y, fr1_w, fr1_b, fr1pv_w, fr1pv_b,
                                   fr2_w, fr3_w, fr2pv_w, fr3pv_w,
                                   fo1_w, fo2_w, fo3_w,
                                   A1h, B1h, A1pvh, B1pvh, WT, (float*)d_out);
  mega<<<NB * 8, 256, 0, stream>>>(A1h, B1h, A1pvh, B1pvh, x,
                                   fr2_b, fr3_b, fr2pv_b, fr3pv_b,
                                   fo1_b, fo2_b, fo3_b, fc_w, fc_b,
                                   WT, (float*)d_out);
}

// Round 8
// 231.420 us; speedup vs baseline: 1.0668x; 1.0668x over previous
//
#include <hip/hip_runtime.h>

typedef __attribute__((ext_vector_type(8))) _Float16 half8;
typedef __attribute__((ext_vector_type(4))) _Float16 half4v;
typedef __attribute__((ext_vector_type(4))) float floatx4;

#define NB 128
#define NN 64
#define NV 14
#define PP 32
#define SS 14
#define HH 128
#define DE 64
#define NCLS 5
#define PITCH 136   // halves; 272 B rows -> max 2-way bank aliasing (free)

// fragment-major weight offsets (halves). layout: [nt][ks][lane][8]
#define OFF_W2   0
#define OFF_W3   16384
#define OFF_W2PV 24576
#define OFF_W3PV 40960
#define OFF_FO1  49152
#define OFF_FO2  69632
#define OFF_FO3  86016

__device__ __forceinline__ floatx4 MFMA(half8 a, half8 b, floatx4 c) {
  return __builtin_amdgcn_mfma_f32_16x16x32_f16(a, b, c, 0, 0, 0);
}

// relu(acc+bias) -> 4 fp16 packed in 2 u32 (rg0|rg1, rg2|rg3)
__device__ __forceinline__ uint2 pack4(floatx4 a, float4 bb) {
  half4v h;
  h[0] = (_Float16)fmaxf(a[0] + bb.x, 0.f);
  h[1] = (_Float16)fmaxf(a[1] + bb.y, 0.f);
  h[2] = (_Float16)fmaxf(a[2] + bb.z, 0.f);
  h[3] = (_Float16)fmaxf(a[3] + bb.w, 0.f);
  union { half4v h4; uint2 u; } cv; cv.h4 = h;
  return cv.u;
}

// ---------------- K0: fp16 layer-1 terms (+bias fold), frag-major weights, d_out zero ----------------
__global__ __launch_bounds__(256) void k0_prep(
    const float* __restrict__ x, const float* __restrict__ y,
    const float* __restrict__ fr1_w, const float* __restrict__ fr1_b,
    const float* __restrict__ fr1pv_w, const float* __restrict__ fr1pv_b,
    const float* __restrict__ fr2_w, const float* __restrict__ fr3_w,
    const float* __restrict__ fr2pv_w, const float* __restrict__ fr3pv_w,
    const float* __restrict__ fo1_w, const float* __restrict__ fo2_w,
    const float* __restrict__ fo3_w,
    _Float16* __restrict__ A1h, _Float16* __restrict__ B1h,
    _Float16* __restrict__ A1pvh, _Float16* __restrict__ B1pvh,
    _Float16* __restrict__ WT, float* __restrict__ dout) {
  int blk = blockIdx.x;
  int tid = threadIdx.x;
  if (blk < 768) {
    // half of one (matrix, batch): 32 rows x 128 cols, K=32
    int mat = blk >> 8, sub = blk & 255;
    int b = sub >> 1, n0 = (sub & 1) << 5;
    __shared__ float sxT[32 * 33];
    for (int i = tid; i < 32 * PP; i += 256) {
      int p = i >> 5, n = i & 31;
      sxT[n * 33 + p] = x[b * (PP * NN) + p * 64 + n0 + n];
    }
    __syncthreads();
    const float* w; _Float16* outp; const float* bias;
    if (mat == 0)      { w = fr1_w;           outp = A1h;   bias = fr1_b; }
    else if (mat == 1) { w = fr1_w + 32 * HH; outp = B1h;   bias = nullptr; }
    else               { w = fr1pv_w;         outp = A1pvh; bias = fr1pv_b; }
    for (int o = tid; o < 32 * 32; o += 256) {
      int n = o >> 5, jc = o & 31;
      float4 acc = {0.f, 0.f, 0.f, 0.f};
      const float* xr = &sxT[n * 33];
#pragma unroll 8
      for (int k = 0; k < PP; k++) {
        float xv = xr[k];
        float4 wv = ((const float4*)w)[k * 32 + jc];
        acc.x += xv * wv.x; acc.y += xv * wv.y;
        acc.z += xv * wv.z; acc.w += xv * wv.w;
      }
      if (bias) {
        float4 bv = ((const float4*)bias)[jc];
        acc.x += bv.x; acc.y += bv.y; acc.z += bv.z; acc.w += bv.w;
      }
      half4v hv;
      hv[0] = (_Float16)acc.x; hv[1] = (_Float16)acc.y;
      hv[2] = (_Float16)acc.z; hv[3] = (_Float16)acc.w;
      *(half4v*)(&outp[(b * NN + n0 + n) * HH + jc * 4]) = hv;
    }
  } else if (blk < 896) {
    int b = blk - 768;
    __shared__ float syT[NV * 15];
    for (int i = tid; i < SS * NV; i += 256) {
      int s = i / NV, v = i - s * NV;
      syT[v * 15 + s] = y[b * (SS * NV) + i];
    }
    __syncthreads();
    const float4* w4 = (const float4*)(fr1pv_w + 32 * HH);
    for (int o = tid; o < NV * 32; o += 256) {
      int v = o >> 5, jc = o & 31;
      float4 acc = {0.f, 0.f, 0.f, 0.f};
#pragma unroll
      for (int s = 0; s < SS; s++) {
        float yv = syT[v * 15 + s];
        float4 wv = w4[s * 32 + jc];
        acc.x += yv * wv.x; acc.y += yv * wv.y;
        acc.z += yv * wv.z; acc.w += yv * wv.w;
      }
      half4v hv;
      hv[0] = (_Float16)acc.x; hv[1] = (_Float16)acc.y;
      hv[2] = (_Float16)acc.z; hv[3] = (_Float16)acc.w;
      *(half4v*)(&B1pvh[(b * NV + v) * HH + jc * 4]) = hv;
    }
  } else if (blk < 952) {
    // frag-major transform, 8 slices per matrix:
    // dst[((nt*NKS+ks)*64 + lane)*8 + j] = src[(ks*32+q*8+j)*N + nt*16+c]
    int t = blk - 896;
    int wid = t >> 3, slice = t & 7;
    const float* src; int N, NKS, NTN; _Float16* dst;
    switch (wid) {
      case 0: src = fr2_w;   N = 128; NKS = 4; NTN = 8; dst = WT + OFF_W2;   break;
      case 1: src = fr3_w;   N = 64;  NKS = 4; NTN = 4; dst = WT + OFF_W3;   break;
      case 2: src = fr2pv_w; N = 128; NKS = 4; NTN = 8; dst = WT + OFF_W2PV; break;
      case 3: src = fr3pv_w; N = 64;  NKS = 4; NTN = 4; dst = WT + OFF_W3PV; break;
      case 4: src = fo1_w;   N = 128; NKS = 5; NTN = 8; dst = WT + OFF_FO1;  break;
      case 5: src = fo2_w;   N = 128; NKS = 4; NTN = 8; dst = WT + OFF_FO2;  break;
      default: src = fo3_w;  N = 64;  NKS = 4; NTN = 4; dst = WT + OFF_FO3;  break;
    }
    int tot = NTN * NKS * 512;
    int sz = tot >> 3;
    int hi = (slice + 1) * sz;
    for (int i = slice * sz + tid; i < hi; i += 256) {
      int j = i & 7, l = (i >> 3) & 63, f = i >> 9;
      int ks = f % NKS, nt = f / NKS;
      int cc = l & 15, qq = l >> 4;
      dst[i] = (_Float16)src[(ks * 32 + qq * 8 + j) * N + nt * 16 + cc];
    }
  } else {
    for (int i = tid; i < NB * NCLS; i += 256) dout[i] = 0.f;
  }
}

// layers 2+3 on one 32-row wave tile (M=32); 4 independent MFMA chains in
// layer2; transposed-C output converted to layer3 A-frags IN REGISTER via
// quad-shuffles (no LDS round-trip, no barrier). Weight fragments come from
// W2fm/W3fm (LDS for pp, global for pv — addrspace inferred after inlining).
template <int DIVR, int NROWS>
__device__ __forceinline__ void layers23(
    const half8 (&hf)[2][4],
    const _Float16* __restrict__ W2fm, const _Float16* __restrict__ W3fm,
    const float* __restrict__ b2, const float* __restrict__ b3,
    float* __restrict__ sEb, int wrow, int chbase, int lane) {
  int c = lane & 15, q = lane >> 4;
  int srcA = c + (((2 * q) & 3) << 4);
  int srcB = c + (((2 * q + 1) & 3) << 4);
  bool selhi = (q >> 1) != 0;
  half8 a2[2][4];
#pragma unroll
  for (int p = 0; p < 4; p++) {
    int nt0 = 2 * p, nt1 = 2 * p + 1;
    floatx4 acc00 = {0.f, 0.f, 0.f, 0.f}, acc01 = {0.f, 0.f, 0.f, 0.f};
    floatx4 acc10 = {0.f, 0.f, 0.f, 0.f}, acc11 = {0.f, 0.f, 0.f, 0.f};
#pragma unroll
    for (int ks = 0; ks < 4; ks++) {
      half8 wf0 = *(const half8*)(&W2fm[((nt0 * 4 + ks) << 9) + (lane << 3)]);
      half8 wf1 = *(const half8*)(&W2fm[((nt1 * 4 + ks) << 9) + (lane << 3)]);
      acc00 = MFMA(wf0, hf[0][ks], acc00);
      acc01 = MFMA(wf0, hf[1][ks], acc01);
      acc10 = MFMA(wf1, hf[0][ks], acc10);
      acc11 = MFMA(wf1, hf[1][ks], acc11);
    }
    float4 bb0 = *(const float4*)(&b2[nt0 * 16 + q * 4]);
    float4 bb1 = *(const float4*)(&b2[nt1 * 16 + q * 4]);
#pragma unroll
    for (int mt = 0; mt < 2; mt++) {
      uint2 u0 = pack4(mt ? acc01 : acc00, bb0);
      uint2 u1 = pack4(mt ? acc11 : acc10, bb1);
      int ax0 = __shfl((int)u0.x, srcA), ax1 = __shfl((int)u1.x, srcA);
      int ay0 = __shfl((int)u0.y, srcA), ay1 = __shfl((int)u1.y, srcA);
      int bx0 = __shfl((int)u0.x, srcB), bx1 = __shfl((int)u1.x, srcB);
      int by0 = __shfl((int)u0.y, srcB), by1 = __shfl((int)u1.y, srcB);
      union { uint4 u; half8 h; } fr;
      fr.u.x = (unsigned)(selhi ? ax1 : ax0);
      fr.u.y = (unsigned)(selhi ? ay1 : ay0);
      fr.u.z = (unsigned)(selhi ? bx1 : bx0);
      fr.u.w = (unsigned)(selhi ? by1 : by0);
      a2[mt][p] = fr.h;
    }
  }
  // layer3: E = h2(A regs) @ W3(B)
#pragma unroll
  for (int nt = 0; nt < 4; nt++) {
    floatx4 e0 = {0.f, 0.f, 0.f, 0.f}, e1 = {0.f, 0.f, 0.f, 0.f};
#pragma unroll
    for (int ks = 0; ks < 4; ks++) {
      half8 wf = *(const half8*)(&W3fm[((nt * 4 + ks) << 9) + (lane << 3)]);
      e0 = MFMA(a2[0][ks], wf, e0);
      e1 = MFMA(a2[1][ks], wf, e1);
    }
    int col = nt * 16 + c;
    float bb = b3[col];
#pragma unroll
    for (int mt = 0; mt < 2; mt++) {
      floatx4 ac = mt ? e1 : e0;
      int rbase = chbase + wrow + mt * 16 + q * 4;
      if (rbase < NROWS) {
        float v0 = fmaxf(ac[0] + bb, 0.f);
        float v1 = fmaxf(ac[1] + bb, 0.f);
        float v2 = fmaxf(ac[2] + bb, 0.f);
        float v3 = fmaxf(ac[3] + bb, 0.f);
        int rrA = rbase / DIVR, rrB = (rbase + 3) / DIVR;
        if (rrA == rrB && rbase + 3 < NROWS) {
          atomicAdd(&sEb[rrA * 64 + col], v0 + v1 + v2 + v3);
        } else {
          float vs[4] = {v0, v1, v2, v3};
#pragma unroll
          for (int rg = 0; rg < 4; rg++) {
            int r2 = rbase + rg;
            if (r2 < NROWS) atomicAdd(&sEb[(r2 / DIVR) * 64 + col], vs[rg]);
          }
        }
      }
    }
  }
}

// ---------------- MEGA: pp + pv edges + node MLP + pool + fc, per (b, 8 nodes) ----------------
__global__ __launch_bounds__(256) void mega(
    const _Float16* __restrict__ A1h, const _Float16* __restrict__ B1h,
    const _Float16* __restrict__ A1pvh, const _Float16* __restrict__ B1pvh,
    const float* __restrict__ x,
    const float* __restrict__ fr2_b, const float* __restrict__ fr3_b,
    const float* __restrict__ fr2pv_b, const float* __restrict__ fr3pv_b,
    const float* __restrict__ fo1_b, const float* __restrict__ fo2_b,
    const float* __restrict__ fo3_b,
    const float* __restrict__ fc_w, const float* __restrict__ fc_b,
    const _Float16* __restrict__ WT, float* __restrict__ out) {
  __shared__ _Float16 sW2[128 * 128];     // 32768 B  pp layer2 weights, frag-major
  __shared__ _Float16 sW3[64 * 128];      // 16384 B  pp layer3 weights, frag-major
  __shared__ _Float16 sB1[64 * PITCH];    // 17408 B; node-stage arrays overlay after edges
  __shared__ _Float16 sA1[8 * PITCH];     // 2176 B
  __shared__ _Float16 sApv[8 * PITCH];    // 2176 B
  __shared__ _Float16 sBpv[14 * PITCH];   // 3808 B
  __shared__ float sEpp[8 * 64];          // 2048 B
  __shared__ float sEpv[8 * 64];          // 2048 B
  __shared__ float sPool[64];             // 256 B   total ~79.1 KB -> 2 blocks/CU
  int tid = threadIdx.x;
  int b = blockIdx.x >> 3, r0 = (blockIdx.x & 7) << 3;
  for (int i = tid; i < 512; i += 256) { sEpp[i] = 0.f; sEpv[i] = 0.f; }
  // stage pp weights (coalesced uint4; identical layout to WT)
  for (int i = tid; i < 2048; i += 256)
    ((uint4*)sW2)[i] = ((const uint4*)(WT + OFF_W2))[i];
  for (int i = tid; i < 1024; i += 256)
    ((uint4*)sW3)[i] = ((const uint4*)(WT + OFF_W3))[i];
  for (int i = tid; i < 64 * 16; i += 256) {
    int row = i >> 4, cc = i & 15;
    *(uint4*)(&sB1[row * PITCH + cc * 8]) = *(const uint4*)(&B1h[(b * NN + row) * HH + cc * 8]);
  }
  for (int i = tid; i < 8 * 16; i += 256) {
    int row = i >> 4, cc = i & 15;
    *(uint4*)(&sA1[row * PITCH + cc * 8]) = *(const uint4*)(&A1h[(b * NN + r0 + row) * HH + cc * 8]);
    *(uint4*)(&sApv[row * PITCH + cc * 8]) = *(const uint4*)(&A1pvh[(b * NN + r0 + row) * HH + cc * 8]);
  }
  for (int i = tid; i < 14 * 16; i += 256) {
    int row = i >> 4, cc = i & 15;
    *(uint4*)(&sBpv[row * PITCH + cc * 8]) = *(const uint4*)(&B1pvh[(b * NV + row) * HH + cc * 8]);
  }
  __syncthreads();
  int lane = tid & 63, wv = tid >> 6;
  int c = lane & 15, q = lane >> 4;
  int wrow = wv * 32;
  // ---- 4 pp chunks of 128 rows (504 real rows: 8 receivers x 63 senders) ----
#pragma unroll 1
  for (int ch = 0; ch < 4; ch++) {
    half8 hf[2][4];
#pragma unroll
    for (int mt = 0; mt < 2; mt++) {
      int rl = ch * 128 + wrow + mt * 16 + c;
      int rr = rl / 63; if (rr > 7) rr = 7;
      int jj = rl - rr * 63; if (jj > 62) jj = 62;
      int s = jj + (jj >= r0 + rr ? 1 : 0);
#pragma unroll
      for (int ks = 0; ks < 4; ks++) {
        half8 av = *(const half8*)(&sA1[rr * PITCH + ks * 32 + q * 8]);
        half8 bv = *(const half8*)(&sB1[s * PITCH + ks * 32 + q * 8]);
        half8 h = av + bv;
#pragma unroll
        for (int j = 0; j < 8; j++) h[j] = h[j] > (_Float16)0.f ? h[j] : (_Float16)0.f;
        hf[mt][ks] = h;
      }
    }
    layers23<63, 504>(hf, sW2, sW3, fr2_b, fr3_b, sEpp, wrow, ch * 128, lane);
  }
  // ---- 1 pv chunk of 128 rows (112 real: 8 k-nodes x 14 vertices), global weights ----
  {
    half8 hf[2][4];
#pragma unroll
    for (int mt = 0; mt < 2; mt++) {
      int rl = wrow + mt * 16 + c;
      int rr = rl / 14; if (rr > 7) rr = 7;
      int v = rl - rr * 14; if (v > 13) v = 13;
#pragma unroll
      for (int ks = 0; ks < 4; ks++) {
        half8 av = *(const half8*)(&sApv[rr * PITCH + ks * 32 + q * 8]);
        half8 bv = *(const half8*)(&sBpv[v * PITCH + ks * 32 + q * 8]);
        half8 h = av + bv;
#pragma unroll
        for (int j = 0; j < 8; j++) h[j] = h[j] > (_Float16)0.f ? h[j] : (_Float16)0.f;
        hf[mt][ks] = h;
      }
    }
    layers23<14, 112>(hf, WT + OFF_W2PV, WT + OFF_W3PV, fr2pv_b, fr3pv_b,
                      sEpv, wrow, 0, lane);
  }
  __syncthreads();   // sEb complete; sB1 dead -> overlay node arrays
  // ---- node stage: C = [x | Ebar_pp | Ebar_pv] for this block's 8 nodes ----
  _Float16* sC  = sB1;                 // 16 x 168 = 5376 B
  _Float16* sHa = sB1 + 16 * 168;      // 16 x PITCH = 4352 B
  _Float16* sHb = sB1 + 16 * 168 + 16 * PITCH;  // 4352 B (total 14080 <= 17408)
  for (int i = tid; i < 16 * 32; i += 256) {
    int row = i >> 5, p = i & 31;
    float v = (row < 8) ? x[b * (PP * NN) + p * 64 + r0 + row] : 0.f;
    sC[row * 168 + p] = (_Float16)v;
  }
  for (int i = tid; i < 16 * 64; i += 256) {
    int row = i >> 6, d = i & 63;
    float vpp = (row < 8) ? sEpp[row * 64 + d] : 0.f;
    float vpv = (row < 8) ? sEpv[row * 64 + d] : 0.f;
    sC[row * 168 + 32 + d] = (_Float16)vpp;
    sC[row * 168 + 96 + d] = (_Float16)vpv;
  }
  __syncthreads();
  // fo1 (K=160), transposed-C; wave owns cols wv*32..+31
  half8 cf[5];
#pragma unroll
  for (int ks = 0; ks < 5; ks++)
    cf[ks] = *(const half8*)(&sC[c * 168 + ks * 32 + q * 8]);
#pragma unroll
  for (int nt2 = 0; nt2 < 2; nt2++) {
    int nt = wv * 2 + nt2;
    floatx4 a0 = {0.f, 0.f, 0.f, 0.f};
#pragma unroll
    for (int ks = 0; ks < 5; ks++) {
      half8 wf = *(const half8*)(&WT[OFF_FO1 + ((nt * 5 + ks) << 9) + (lane << 3)]);
      a0 = MFMA(wf, cf[ks], a0);
    }
    float4 bb = *(const float4*)(&fo1_b[nt * 16 + q * 4]);
    half4v h0;
    h0[0] = (_Float16)fmaxf(a0[0] + bb.x, 0.f);
    h0[1] = (_Float16)fmaxf(a0[1] + bb.y, 0.f);
    h0[2] = (_Float16)fmaxf(a0[2] + bb.z, 0.f);
    h0[3] = (_Float16)fmaxf(a0[3] + bb.w, 0.f);
    *(half4v*)(&sHa[c * PITCH + nt * 16 + q * 4]) = h0;
  }
  __syncthreads();
  // fo2 (K=128), transposed-C
  half8 g1[4];
#pragma unroll
  for (int ks = 0; ks < 4; ks++)
    g1[ks] = *(const half8*)(&sHa[c * PITCH + ks * 32 + q * 8]);
#pragma unroll
  for (int nt2 = 0; nt2 < 2; nt2++) {
    int nt = wv * 2 + nt2;
    floatx4 a0 = {0.f, 0.f, 0.f, 0.f};
#pragma unroll
    for (int ks = 0; ks < 4; ks++) {
      half8 wf = *(const half8*)(&WT[OFF_FO2 + ((nt * 4 + ks) << 9) + (lane << 3)]);
      a0 = MFMA(wf, g1[ks], a0);
    }
    float4 bb = *(const float4*)(&fo2_b[nt * 16 + q * 4]);
    half4v h0;
    h0[0] = (_Float16)fmaxf(a0[0] + bb.x, 0.f);
    h0[1] = (_Float16)fmaxf(a0[1] + bb.y, 0.f);
    h0[2] = (_Float16)fmaxf(a0[2] + bb.z, 0.f);
    h0[3] = (_Float16)fmaxf(a0[3] + bb.w, 0.f);
    *(half4v*)(&sHb[c * PITCH + nt * 16 + q * 4]) = h0;
  }
  __syncthreads();
  // fo3 (N=64): wave owns 16 cols; pool over the 8 real nodes
  half8 g2[4];
#pragma unroll
  for (int ks = 0; ks < 4; ks++)
    g2[ks] = *(const half8*)(&sHb[c * PITCH + ks * 32 + q * 8]);
  floatx4 e0 = {0.f, 0.f, 0.f, 0.f};
#pragma unroll
  for (int ks = 0; ks < 4; ks++) {
    half8 wf = *(const half8*)(&WT[OFF_FO3 + ((wv * 4 + ks) << 9) + (lane << 3)]);
    e0 = MFMA(g2[ks], wf, e0);
  }
  float bb3 = fo3_b[wv * 16 + c];
  float s = 0.f;
  if (q < 2) {
#pragma unroll
    for (int rg = 0; rg < 4; rg++) s += fmaxf(e0[rg] + bb3, 0.f);
  }
  s += __shfl_xor(s, 16);
  if (lane < 16) sPool[wv * 16 + c] = s;
  __syncthreads();
  if (tid < NCLS) {
    float o = (r0 == 0) ? fc_b[tid] : 0.f;
#pragma unroll
    for (int d = 0; d < 64; d++) o += sPool[d] * fc_w[d * NCLS + tid];
    atomicAdd(&out[b * NCLS + tid], o);
  }
}

extern "C" void kernel_launch(void* const* d_in, const int* in_sizes, int n_in,
                              void* d_out, int out_size, void* d_ws, size_t ws_size,
                              hipStream_t stream) {
  const float* x = (const float*)d_in[0];
  const float* y = (const float*)d_in[1];
  const float* fr1_w = (const float*)d_in[2];  const float* fr1_b = (const float*)d_in[3];
  const float* fr2_w = (const float*)d_in[4];  const float* fr2_b = (const float*)d_in[5];
  const float* fr3_w = (const float*)d_in[6];  const float* fr3_b = (const float*)d_in[7];
  const float* fr1pv_w = (const float*)d_in[8];  const float* fr1pv_b = (const float*)d_in[9];
  const float* fr2pv_w = (const float*)d_in[10]; const float* fr2pv_b = (const float*)d_in[11];
  const float* fr3pv_w = (const float*)d_in[12]; const float* fr3pv_b = (const float*)d_in[13];
  const float* fo1_w = (const float*)d_in[14];  const float* fo1_b = (const float*)d_in[15];
  const float* fo2_w = (const float*)d_in[16];  const float* fo2_b = (const float*)d_in[17];
  const float* fo3_w = (const float*)d_in[18];  const float* fo3_b = (const float*)d_in[19];
  const float* fc_w = (const float*)d_in[20];   const float* fc_b = (const float*)d_in[21];

  char* ws = (char*)d_ws;
  _Float16* A1h   = (_Float16*)(ws);                 // [128][64][128] fp16 (bias folded)
  _Float16* B1h   = (_Float16*)(ws + (2u << 20));
  _Float16* A1pvh = (_Float16*)(ws + (4u << 20));    // (bias folded)
  _Float16* B1pvh = (_Float16*)(ws + (6u << 20));    // [128][14][128] fp16
  _Float16* WT    = (_Float16*)(ws + (7u << 20));    // frag-major fp16 weights (~200 KB)

  k0_prep<<<953, 256, 0, stream>>>(x, y, fr1_w, fr1_b, fr1pv_w, fr1pv_b,
                                   fr2_w, fr3_w, fr2pv_w, fr3pv_w,
                                   fo1_w, fo2_w, fo3_w,
                                   A1h, B1h, A1pvh, B1pvh, WT, (float*)d_out);
  mega<<<NB * 8, 256, 0, stream>>>(A1h, B1h, A1pvh, B1pvh, x,
                                   fr2_b, fr3_b, fr2pv_b, fr3pv_b,
                                   fo1_b, fo2_b, fo3_b, fc_w, fc_b,
                                   WT, (float*)d_out);
}

// Round 9
// 228.291 us; speedup vs baseline: 1.0814x; 1.0137x over previous
//
#include <hip/hip_runtime.h>

typedef __attribute__((ext_vector_type(8))) _Float16 half8;
typedef __attribute__((ext_vector_type(4))) _Float16 half4v;
typedef __attribute__((ext_vector_type(4))) float floatx4;

#define NB 128
#define NN 64
#define NV 14
#define PP 32
#define SS 14
#define HH 128
#define DE 64
#define NCLS 5
#define PITCH 136   // halves; 272 B rows -> max 2-way bank aliasing (free)

// fragment-major weight offsets (halves). layout: [nt][ks][lane][8]
#define OFF_W2   0
#define OFF_W3   16384
#define OFF_W2PV 24576
#define OFF_W3PV 40960
#define OFF_FO1  49152
#define OFF_FO2  69632
#define OFF_FO3  86016

__device__ __forceinline__ floatx4 MFMA(half8 a, half8 b, floatx4 c) {
  return __builtin_amdgcn_mfma_f32_16x16x32_f16(a, b, c, 0, 0, 0);
}

// ---------------- K0: fp16 layer-1 terms (+bias fold), frag-major weights, d_out zero ----------------
__global__ __launch_bounds__(256) void k0_prep(
    const float* __restrict__ x, const float* __restrict__ y,
    const float* __restrict__ fr1_w, const float* __restrict__ fr1_b,
    const float* __restrict__ fr1pv_w, const float* __restrict__ fr1pv_b,
    const float* __restrict__ fr2_w, const float* __restrict__ fr3_w,
    const float* __restrict__ fr2pv_w, const float* __restrict__ fr3pv_w,
    const float* __restrict__ fo1_w, const float* __restrict__ fo2_w,
    const float* __restrict__ fo3_w,
    _Float16* __restrict__ A1h, _Float16* __restrict__ B1h,
    _Float16* __restrict__ A1pvh, _Float16* __restrict__ B1pvh,
    _Float16* __restrict__ WT, float* __restrict__ dout) {
  int blk = blockIdx.x;
  int tid = threadIdx.x;
  if (blk < 768) {
    int mat = blk >> 8, sub = blk & 255;
    int b = sub >> 1, n0 = (sub & 1) << 5;
    __shared__ float sxT[32 * 33];
    for (int i = tid; i < 32 * PP; i += 256) {
      int p = i >> 5, n = i & 31;
      sxT[n * 33 + p] = x[b * (PP * NN) + p * 64 + n0 + n];
    }
    __syncthreads();
    const float* w; _Float16* outp; const float* bias;
    if (mat == 0)      { w = fr1_w;           outp = A1h;   bias = fr1_b; }
    else if (mat == 1) { w = fr1_w + 32 * HH; outp = B1h;   bias = nullptr; }
    else               { w = fr1pv_w;         outp = A1pvh; bias = fr1pv_b; }
    for (int o = tid; o < 32 * 32; o += 256) {
      int n = o >> 5, jc = o & 31;
      float4 acc = {0.f, 0.f, 0.f, 0.f};
      const float* xr = &sxT[n * 33];
#pragma unroll 8
      for (int k = 0; k < PP; k++) {
        float xv = xr[k];
        float4 wv = ((const float4*)w)[k * 32 + jc];
        acc.x += xv * wv.x; acc.y += xv * wv.y;
        acc.z += xv * wv.z; acc.w += xv * wv.w;
      }
      if (bias) {
        float4 bv = ((const float4*)bias)[jc];
        acc.x += bv.x; acc.y += bv.y; acc.z += bv.z; acc.w += bv.w;
      }
      half4v hv;
      hv[0] = (_Float16)acc.x; hv[1] = (_Float16)acc.y;
      hv[2] = (_Float16)acc.z; hv[3] = (_Float16)acc.w;
      *(half4v*)(&outp[(b * NN + n0 + n) * HH + jc * 4]) = hv;
    }
  } else if (blk < 896) {
    int b = blk - 768;
    __shared__ float syT[NV * 15];
    for (int i = tid; i < SS * NV; i += 256) {
      int s = i / NV, v = i - s * NV;
      syT[v * 15 + s] = y[b * (SS * NV) + i];
    }
    __syncthreads();
    const float4* w4 = (const float4*)(fr1pv_w + 32 * HH);
    for (int o = tid; o < NV * 32; o += 256) {
      int v = o >> 5, jc = o & 31;
      float4 acc = {0.f, 0.f, 0.f, 0.f};
#pragma unroll
      for (int s = 0; s < SS; s++) {
        float yv = syT[v * 15 + s];
        float4 wv = w4[s * 32 + jc];
        acc.x += yv * wv.x; acc.y += yv * wv.y;
        acc.z += yv * wv.z; acc.w += yv * wv.w;
      }
      half4v hv;
      hv[0] = (_Float16)acc.x; hv[1] = (_Float16)acc.y;
      hv[2] = (_Float16)acc.z; hv[3] = (_Float16)acc.w;
      *(half4v*)(&B1pvh[(b * NV + v) * HH + jc * 4]) = hv;
    }
  } else if (blk < 952) {
    // frag-major transform, 8 slices per matrix:
    // dst[((nt*NKS+ks)*64 + lane)*8 + j] = src[(ks*32+q*8+j)*N + nt*16+c]
    int t = blk - 896;
    int wid = t >> 3, slice = t & 7;
    const float* src; int N, NKS, NTN; _Float16* dst;
    switch (wid) {
      case 0: src = fr2_w;   N = 128; NKS = 4; NTN = 8; dst = WT + OFF_W2;   break;
      case 1: src = fr3_w;   N = 64;  NKS = 4; NTN = 4; dst = WT + OFF_W3;   break;
      case 2: src = fr2pv_w; N = 128; NKS = 4; NTN = 8; dst = WT + OFF_W2PV; break;
      case 3: src = fr3pv_w; N = 64;  NKS = 4; NTN = 4; dst = WT + OFF_W3PV; break;
      case 4: src = fo1_w;   N = 128; NKS = 5; NTN = 8; dst = WT + OFF_FO1;  break;
      case 5: src = fo2_w;   N = 128; NKS = 4; NTN = 8; dst = WT + OFF_FO2;  break;
      default: src = fo3_w;  N = 64;  NKS = 4; NTN = 4; dst = WT + OFF_FO3;  break;
    }
    int tot = NTN * NKS * 512;
    int sz = tot >> 3;
    int hi = (slice + 1) * sz;
    for (int i = slice * sz + tid; i < hi; i += 256) {
      int j = i & 7, l = (i >> 3) & 63, f = i >> 9;
      int ks = f % NKS, nt = f / NKS;
      int cc = l & 15, qq = l >> 4;
      dst[i] = (_Float16)src[(ks * 32 + qq * 8 + j) * N + nt * 16 + cc];
    }
  } else {
    for (int i = tid; i < NB * NCLS; i += 256) dout[i] = 0.f;
  }
}

// ---------------- EDGE_PP: weights in registers; wave owns output-neuron tiles ----------------
// block = (b, 4 receivers) = 252 rows in 4 chunks of 64. Per chunk:
//   layer2: each wave computes its 2 nt tiles (32 neurons) for ALL 64 rows -> sH2
//   layer3: each wave computes its 1 nt tile (16 cols) for all rows -> sEb atomics
__global__ __launch_bounds__(256) void edge_pp(
    const _Float16* __restrict__ A1h, const _Float16* __restrict__ B1h,
    const float* __restrict__ fr2_b, const float* __restrict__ fr3_b,
    const _Float16* __restrict__ WT, float* __restrict__ Epp) {
  __shared__ _Float16 sB1[64 * PITCH];   // 17408 B
  __shared__ _Float16 sA1[4 * PITCH];    // 1088 B
  __shared__ _Float16 sH2[64 * PITCH];   // 17408 B
  __shared__ float sEb[4 * 64];          // 1024 B   total ~36.9 KB
  int tid = threadIdx.x;
  int b = blockIdx.x >> 4, r0 = (blockIdx.x & 15) << 2;
  sEb[tid & 255] = 0.f;
  for (int i = tid; i < 1024; i += 256) {
    int row = i >> 4, cc = i & 15;
    *(uint4*)(&sB1[row * PITCH + cc * 8]) = *(const uint4*)(&B1h[(b * NN + row) * HH + cc * 8]);
  }
  if (tid < 64) {
    int row = tid >> 4, cc = tid & 15;
    *(uint4*)(&sA1[row * PITCH + cc * 8]) = *(const uint4*)(&A1h[(b * NN + r0 + row) * HH + cc * 8]);
  }
  int lane = tid & 63, wv = tid >> 6;
  int c = lane & 15, q = lane >> 4;
  // persistent register weights: W2 frags for nts {2wv,2wv+1}, W3 frag for nt=wv
  half8 w2f[2][4], w3f[4];
#pragma unroll
  for (int nt2 = 0; nt2 < 2; nt2++)
#pragma unroll
    for (int ks = 0; ks < 4; ks++)
      w2f[nt2][ks] = *(const half8*)(&WT[OFF_W2 + ((((wv * 2 + nt2) * 4 + ks)) << 9) + (lane << 3)]);
#pragma unroll
  for (int ks = 0; ks < 4; ks++)
    w3f[ks] = *(const half8*)(&WT[OFF_W3 + (((wv * 4 + ks)) << 9) + (lane << 3)]);
  float4 bb2[2];
  bb2[0] = *(const float4*)(&fr2_b[(wv * 2) * 16 + q * 4]);
  bb2[1] = *(const float4*)(&fr2_b[(wv * 2 + 1) * 16 + q * 4]);
  float bb3 = fr3_b[wv * 16 + c];
  __syncthreads();
#pragma unroll 1
  for (int ch = 0; ch < 4; ch++) {
    int base = ch * 64;
    // ---- layer2: 4 row-tiles x 2 nts ----
#pragma unroll 1
    for (int rt = 0; rt < 4; rt++) {
      int rowl = base + rt * 16 + c;
      int rr = rowl / 63; if (rr > 3) rr = 3;
      int jj = rowl - rr * 63; if (jj > 62) jj = 62;
      int s = jj + (jj >= r0 + rr ? 1 : 0);
      half8 hf[4];
#pragma unroll
      for (int ks = 0; ks < 4; ks++) {
        half8 av = *(const half8*)(&sA1[rr * PITCH + ks * 32 + q * 8]);
        half8 bv = *(const half8*)(&sB1[s * PITCH + ks * 32 + q * 8]);
        half8 h = av + bv;
#pragma unroll
        for (int j = 0; j < 8; j++) h[j] = h[j] > (_Float16)0.f ? h[j] : (_Float16)0.f;
        hf[ks] = h;
      }
#pragma unroll
      for (int nt2 = 0; nt2 < 2; nt2++) {
        floatx4 acc = {0.f, 0.f, 0.f, 0.f};
#pragma unroll
        for (int ks = 0; ks < 4; ks++) acc = MFMA(w2f[nt2][ks], hf[ks], acc);
        half4v h0;
        h0[0] = (_Float16)fmaxf(acc[0] + bb2[nt2].x, 0.f);
        h0[1] = (_Float16)fmaxf(acc[1] + bb2[nt2].y, 0.f);
        h0[2] = (_Float16)fmaxf(acc[2] + bb2[nt2].z, 0.f);
        h0[3] = (_Float16)fmaxf(acc[3] + bb2[nt2].w, 0.f);
        *(half4v*)(&sH2[(rt * 16 + c) * PITCH + (wv * 2 + nt2) * 16 + q * 4]) = h0;
      }
    }
    __syncthreads();
    // ---- layer3: 4 row-tiles x 1 nt (cols wv*16..+15) ----
#pragma unroll 1
    for (int rt = 0; rt < 4; rt++) {
      half8 a2[4];
#pragma unroll
      for (int ks = 0; ks < 4; ks++)
        a2[ks] = *(const half8*)(&sH2[(rt * 16 + c) * PITCH + ks * 32 + q * 8]);
      floatx4 e = {0.f, 0.f, 0.f, 0.f};
#pragma unroll
      for (int ks = 0; ks < 4; ks++) e = MFMA(a2[ks], w3f[ks], e);
      int col = wv * 16 + c;
      int rbase = base + rt * 16 + q * 4;
      if (rbase < 252) {
        float v0 = fmaxf(e[0] + bb3, 0.f);
        float v1 = fmaxf(e[1] + bb3, 0.f);
        float v2 = fmaxf(e[2] + bb3, 0.f);
        float v3 = fmaxf(e[3] + bb3, 0.f);
        int rrA = rbase / 63, rrB = (rbase + 3) / 63;
        if (rrA == rrB && rbase + 3 < 252) {
          atomicAdd(&sEb[rrA * 64 + col], v0 + v1 + v2 + v3);
        } else {
          float vs[4] = {v0, v1, v2, v3};
#pragma unroll
          for (int rg = 0; rg < 4; rg++) {
            int r2 = rbase + rg;
            if (r2 < 252) atomicAdd(&sEb[(r2 / 63) * 64 + col], vs[rg]);
          }
        }
      }
    }
    __syncthreads();
  }
  Epp[(b * NN + r0 + (tid >> 6)) * DE + (tid & 63)] = sEb[tid];
}

// ---------------- EDGE_PV: same structure; block = (b, 8 k-nodes) = 112 rows, 2 chunks ----------------
__global__ __launch_bounds__(256) void edge_pv(
    const _Float16* __restrict__ A1pvh, const _Float16* __restrict__ B1pvh,
    const float* __restrict__ fr2pv_b, const float* __restrict__ fr3pv_b,
    const _Float16* __restrict__ WT, float* __restrict__ Epv) {
  __shared__ _Float16 sApv[8 * PITCH];    // 2176 B
  __shared__ _Float16 sBpv[14 * PITCH];   // 3808 B
  __shared__ _Float16 sH2[64 * PITCH];    // 17408 B
  __shared__ float sEb[8 * 64];           // 2048 B   total ~25.4 KB
  int tid = threadIdx.x;
  int b = blockIdx.x >> 3, k0g = (blockIdx.x & 7) << 3;
  for (int i = tid; i < 512; i += 256) sEb[i] = 0.f;
  if (tid < 128) {
    int row = tid >> 4, cc = tid & 15;
    *(uint4*)(&sApv[row * PITCH + cc * 8]) = *(const uint4*)(&A1pvh[(b * NN + k0g + row) * HH + cc * 8]);
  }
  for (int i = tid; i < 14 * 16; i += 256) {
    int row = i >> 4, cc = i & 15;
    *(uint4*)(&sBpv[row * PITCH + cc * 8]) = *(const uint4*)(&B1pvh[(b * NV + row) * HH + cc * 8]);
  }
  int lane = tid & 63, wv = tid >> 6;
  int c = lane & 15, q = lane >> 4;
  half8 w2f[2][4], w3f[4];
#pragma unroll
  for (int nt2 = 0; nt2 < 2; nt2++)
#pragma unroll
    for (int ks = 0; ks < 4; ks++)
      w2f[nt2][ks] = *(const half8*)(&WT[OFF_W2PV + ((((wv * 2 + nt2) * 4 + ks)) << 9) + (lane << 3)]);
#pragma unroll
  for (int ks = 0; ks < 4; ks++)
    w3f[ks] = *(const half8*)(&WT[OFF_W3PV + (((wv * 4 + ks)) << 9) + (lane << 3)]);
  float4 bb2[2];
  bb2[0] = *(const float4*)(&fr2pv_b[(wv * 2) * 16 + q * 4]);
  bb2[1] = *(const float4*)(&fr2pv_b[(wv * 2 + 1) * 16 + q * 4]);
  float bb3 = fr3pv_b[wv * 16 + c];
  __syncthreads();
#pragma unroll 1
  for (int ch = 0; ch < 2; ch++) {
    int base = ch * 64;
#pragma unroll 1
    for (int rt = 0; rt < 4; rt++) {
      int rowl = base + rt * 16 + c;
      int rr = rowl / 14; if (rr > 7) rr = 7;
      int v = rowl - rr * 14; if (v > 13) v = 13;
      half8 hf[4];
#pragma unroll
      for (int ks = 0; ks < 4; ks++) {
        half8 av = *(const half8*)(&sApv[rr * PITCH + ks * 32 + q * 8]);
        half8 bv = *(const half8*)(&sBpv[v * PITCH + ks * 32 + q * 8]);
        half8 h = av + bv;
#pragma unroll
        for (int j = 0; j < 8; j++) h[j] = h[j] > (_Float16)0.f ? h[j] : (_Float16)0.f;
        hf[ks] = h;
      }
#pragma unroll
      for (int nt2 = 0; nt2 < 2; nt2++) {
        floatx4 acc = {0.f, 0.f, 0.f, 0.f};
#pragma unroll
        for (int ks = 0; ks < 4; ks++) acc = MFMA(w2f[nt2][ks], hf[ks], acc);
        half4v h0;
        h0[0] = (_Float16)fmaxf(acc[0] + bb2[nt2].x, 0.f);
        h0[1] = (_Float16)fmaxf(acc[1] + bb2[nt2].y, 0.f);
        h0[2] = (_Float16)fmaxf(acc[2] + bb2[nt2].z, 0.f);
        h0[3] = (_Float16)fmaxf(acc[3] + bb2[nt2].w, 0.f);
        *(half4v*)(&sH2[(rt * 16 + c) * PITCH + (wv * 2 + nt2) * 16 + q * 4]) = h0;
      }
    }
    __syncthreads();
#pragma unroll 1
    for (int rt = 0; rt < 4; rt++) {
      half8 a2[4];
#pragma unroll
      for (int ks = 0; ks < 4; ks++)
        a2[ks] = *(const half8*)(&sH2[(rt * 16 + c) * PITCH + ks * 32 + q * 8]);
      floatx4 e = {0.f, 0.f, 0.f, 0.f};
#pragma unroll
      for (int ks = 0; ks < 4; ks++) e = MFMA(a2[ks], w3f[ks], e);
      int col = wv * 16 + c;
      int rbase = base + rt * 16 + q * 4;
      if (rbase < 112) {
        float v0 = fmaxf(e[0] + bb3, 0.f);
        float v1 = fmaxf(e[1] + bb3, 0.f);
        float v2 = fmaxf(e[2] + bb3, 0.f);
        float v3 = fmaxf(e[3] + bb3, 0.f);
        int rrA = rbase / 14, rrB = (rbase + 3) / 14;
        if (rrA == rrB && rbase + 3 < 112) {
          atomicAdd(&sEb[rrA * 64 + col], v0 + v1 + v2 + v3);
        } else {
          float vs[4] = {v0, v1, v2, v3};
#pragma unroll
          for (int rg = 0; rg < 4; rg++) {
            int r2 = rbase + rg;
            if (r2 < 112) atomicAdd(&sEb[(r2 / 14) * 64 + col], vs[rg]);
          }
        }
      }
    }
    __syncthreads();
  }
  for (int i = tid; i < 512; i += 256)
    Epv[(b * NN + k0g + (i >> 6)) * DE + (i & 63)] = sEb[i];
}

// ---------------- NODE: C=[x|Epp|Epv] -> fo1,fo2,fo3 -> pool -> fc; block=(b, 8 nodes) ----------------
__global__ __launch_bounds__(256) void node_out(
    const float* __restrict__ x, const float* __restrict__ Epp,
    const float* __restrict__ Epv,
    const float* __restrict__ fo1_b, const float* __restrict__ fo2_b,
    const float* __restrict__ fo3_b,
    const float* __restrict__ fc_w, const float* __restrict__ fc_b,
    const _Float16* __restrict__ WT, float* __restrict__ out) {
  __shared__ _Float16 sC[16 * 168];
  __shared__ _Float16 sHa[16 * PITCH];
  __shared__ _Float16 sHb[16 * PITCH];
  __shared__ float sPool[64];
  int tid = threadIdx.x;
  int b = blockIdx.x >> 3, r0 = (blockIdx.x & 7) << 3;
  for (int i = tid; i < 16 * 32; i += 256) {
    int row = i >> 5, p = i & 31;
    float v = (row < 8) ? x[b * (PP * NN) + p * 64 + r0 + row] : 0.f;
    sC[row * 168 + p] = (_Float16)v;
  }
  for (int i = tid; i < 16 * 64; i += 256) {
    int row = i >> 6, d = i & 63;
    float vpp = (row < 8) ? Epp[(b * NN + r0 + row) * DE + d] : 0.f;
    float vpv = (row < 8) ? Epv[(b * NN + r0 + row) * DE + d] : 0.f;
    sC[row * 168 + 32 + d] = (_Float16)vpp;
    sC[row * 168 + 96 + d] = (_Float16)vpv;
  }
  __syncthreads();
  int lane = tid & 63, wv = tid >> 6;
  int c = lane & 15, q = lane >> 4;
  // fo1 (K=160), transposed-C; wave owns cols wv*32..+31
  half8 cf[5];
#pragma unroll
  for (int ks = 0; ks < 5; ks++)
    cf[ks] = *(const half8*)(&sC[c * 168 + ks * 32 + q * 8]);
#pragma unroll
  for (int nt2 = 0; nt2 < 2; nt2++) {
    int nt = wv * 2 + nt2;
    floatx4 a0 = {0.f, 0.f, 0.f, 0.f};
#pragma unroll
    for (int ks = 0; ks < 5; ks++) {
      half8 wf = *(const half8*)(&WT[OFF_FO1 + ((nt * 5 + ks) << 9) + (lane << 3)]);
      a0 = MFMA(wf, cf[ks], a0);
    }
    float4 bb = *(const float4*)(&fo1_b[nt * 16 + q * 4]);
    half4v h0;
    h0[0] = (_Float16)fmaxf(a0[0] + bb.x, 0.f);
    h0[1] = (_Float16)fmaxf(a0[1] + bb.y, 0.f);
    h0[2] = (_Float16)fmaxf(a0[2] + bb.z, 0.f);
    h0[3] = (_Float16)fmaxf(a0[3] + bb.w, 0.f);
    *(half4v*)(&sHa[c * PITCH + nt * 16 + q * 4]) = h0;
  }
  __syncthreads();
  // fo2 (K=128), transposed-C
  half8 g1[4];
#pragma unroll
  for (int ks = 0; ks < 4; ks++)
    g1[ks] = *(const half8*)(&sHa[c * PITCH + ks * 32 + q * 8]);
#pragma unroll
  for (int nt2 = 0; nt2 < 2; nt2++) {
    int nt = wv * 2 + nt2;
    floatx4 a0 = {0.f, 0.f, 0.f, 0.f};
#pragma unroll
    for (int ks = 0; ks < 4; ks++) {
      half8 wf = *(const half8*)(&WT[OFF_FO2 + ((nt * 4 + ks) << 9) + (lane << 3)]);
      a0 = MFMA(wf, g1[ks], a0);
    }
    float4 bb = *(const float4*)(&fo2_b[nt * 16 + q * 4]);
    half4v h0;
    h0[0] = (_Float16)fmaxf(a0[0] + bb.x, 0.f);
    h0[1] = (_Float16)fmaxf(a0[1] + bb.y, 0.f);
    h0[2] = (_Float16)fmaxf(a0[2] + bb.z, 0.f);
    h0[3] = (_Float16)fmaxf(a0[3] + bb.w, 0.f);
    *(half4v*)(&sHb[c * PITCH + nt * 16 + q * 4]) = h0;
  }
  __syncthreads();
  // fo3 (N=64): wave owns 16 cols; pool over the 8 real nodes
  half8 g2[4];
#pragma unroll
  for (int ks = 0; ks < 4; ks++)
    g2[ks] = *(const half8*)(&sHb[c * PITCH + ks * 32 + q * 8]);
  floatx4 e0 = {0.f, 0.f, 0.f, 0.f};
#pragma unroll
  for (int ks = 0; ks < 4; ks++) {
    half8 wf = *(const half8*)(&WT[OFF_FO3 + ((wv * 4 + ks) << 9) + (lane << 3)]);
    e0 = MFMA(g2[ks], wf, e0);
  }
  float bb3 = fo3_b[wv * 16 + c];
  float s = 0.f;
  if (q < 2) {
#pragma unroll
    for (int rg = 0; rg < 4; rg++) s += fmaxf(e0[rg] + bb3, 0.f);
  }
  s += __shfl_xor(s, 16);
  if (lane < 16) sPool[wv * 16 + c] = s;
  __syncthreads();
  if (tid < NCLS) {
    float o = ((blockIdx.x & 7) == 0) ? fc_b[tid] : 0.f;
#pragma unroll
    for (int d = 0; d < 64; d++) o += sPool[d] * fc_w[d * NCLS + tid];
    atomicAdd(&out[b * NCLS + tid], o);
  }
}

extern "C" void kernel_launch(void* const* d_in, const int* in_sizes, int n_in,
                              void* d_out, int out_size, void* d_ws, size_t ws_size,
                              hipStream_t stream) {
  const float* x = (const float*)d_in[0];
  const float* y = (const float*)d_in[1];
  const float* fr1_w = (const float*)d_in[2];  const float* fr1_b = (const float*)d_in[3];
  const float* fr2_w = (const float*)d_in[4];  const float* fr2_b = (const float*)d_in[5];
  const float* fr3_w = (const float*)d_in[6];  const float* fr3_b = (const float*)d_in[7];
  const float* fr1pv_w = (const float*)d_in[8];  const float* fr1pv_b = (const float*)d_in[9];
  const float* fr2pv_w = (const float*)d_in[10]; const float* fr2pv_b = (const float*)d_in[11];
  const float* fr3pv_w = (const float*)d_in[12]; const float* fr3pv_b = (const float*)d_in[13];
  const float* fo1_w = (const float*)d_in[14];  const float* fo1_b = (const float*)d_in[15];
  const float* fo2_w = (const float*)d_in[16];  const float* fo2_b = (const float*)d_in[17];
  const float* fo3_w = (const float*)d_in[18];  const float* fo3_b = (const float*)d_in[19];
  const float* fc_w = (const float*)d_in[20];   const float* fc_b = (const float*)d_in[21];

  char* ws = (char*)d_ws;
  _Float16* A1h   = (_Float16*)(ws);                 // [128][64][128] fp16 (bias folded)
  _Float16* B1h   = (_Float16*)(ws + (2u << 20));
  _Float16* A1pvh = (_Float16*)(ws + (4u << 20));    // (bias folded)
  _Float16* B1pvh = (_Float16*)(ws + (6u << 20));    // [128][14][128] fp16
  _Float16* WT    = (_Float16*)(ws + (7u << 20));    // frag-major fp16 weights (~200 KB)
  float* Epp      = (float*)(ws + (8u << 20));       // [128][64][64] f32
  float* Epv      = (float*)(ws + (10u << 20));      // [128][64][64] f32

  k0_prep<<<953, 256, 0, stream>>>(x, y, fr1_w, fr1_b, fr1pv_w, fr1pv_b,
                                   fr2_w, fr3_w, fr2pv_w, fr3pv_w,
                                   fo1_w, fo2_w, fo3_w,
                                   A1h, B1h, A1pvh, B1pvh, WT, (float*)d_out);
  edge_pp<<<NB * 16, 256, 0, stream>>>(A1h, B1h, fr2_b, fr3_b, WT, Epp);
  edge_pv<<<NB * 8, 256, 0, stream>>>(A1pvh, B1pvh, fr2pv_b, fr3pv_b, WT, Epv);
  node_out<<<NB * 8, 256, 0, stream>>>(x, Epp, Epv, fo1_b, fo2_b, fo3_b,
                                       fc_w, fc_b, WT, (float*)d_out);
}